// Round 3
// baseline (5788.805 us; speedup 1.0000x reference)
//
#include <hip/hip_runtime.h>
#include <math.h>

#define T_STEPS 128
#define B_SZ 128
#define D_SZ 1024
#define H_SZ 1024
#define G4 4096
#define KW 2048  // rows of W = D+H

typedef __attribute__((ext_vector_type(8))) short bf16x8;
typedef __attribute__((ext_vector_type(4))) float f32x4;
typedef unsigned short ushort_t;
typedef unsigned int uint_t;

__device__ __forceinline__ float sigf(float x) { return 1.0f / (1.0f + __expf(-x)); }
// tanh(x) = 1 - 2*sigmoid(-2x)
__device__ __forceinline__ float tanhfast(float x) { return 1.0f - 2.0f * sigf(-2.0f * x); }

__device__ __forceinline__ ushort_t f2bf(float f) {
  uint_t u = __float_as_uint(f);
  return (ushort_t)((u + 0x7fffu + ((u >> 16) & 1u)) >> 16);
}
__device__ __forceinline__ float bf2f(ushort_t s) {
  return __uint_as_float(((uint_t)s) << 16);
}

// ---------------------------------------------------------------------------
// x fp32 [16384][1024] -> bf16 same layout. 8 elems/thread.
// ---------------------------------------------------------------------------
__global__ __launch_bounds__(256) void convert_x(const float* __restrict__ x,
                                                 ushort_t* __restrict__ xbf) {
  const size_t i8 = ((size_t)blockIdx.x * 256 + threadIdx.x) * 8;
  if (i8 + 8 > (size_t)T_STEPS * B_SZ * D_SZ) return;
  float4 a = *(const float4*)&x[i8];
  float4 b = *(const float4*)&x[i8 + 4];
  ushort_t o[8] = {f2bf(a.x), f2bf(a.y), f2bf(a.z), f2bf(a.w),
                   f2bf(b.x), f2bf(b.y), f2bf(b.z), f2bf(b.w)};
  *(uint4*)&xbf[i8] = *(uint4*)o;
}

// ---------------------------------------------------------------------------
// W fp32 [2048][4096] -> WT bf16 [4096][2048]  (WT[n][k] = W[k][n])
// ---------------------------------------------------------------------------
__global__ __launch_bounds__(256) void transpose_w(const float* __restrict__ W,
                                                   ushort_t* __restrict__ WT) {
  __shared__ float t[32][33];
  const int tx = threadIdx.x & 31;
  const int ty = threadIdx.x >> 5;  // 0..7
  const int k0 = blockIdx.x * 32;
  const int n0 = blockIdx.y * 32;
#pragma unroll
  for (int i = 0; i < 4; ++i)
    t[ty + i * 8][tx] = W[(size_t)(k0 + ty + i * 8) * G4 + n0 + tx];
  __syncthreads();
#pragma unroll
  for (int i = 0; i < 4; ++i)
    WT[(size_t)(n0 + ty + i * 8) * KW + k0 + tx] = f2bf(t[tx][ty + i * 8]);
}

// ---------------------------------------------------------------------------
// hbf0 = bf16(h0 * (1-reset[0])), c0m = c0 * (1-reset[0])
// ---------------------------------------------------------------------------
__global__ __launch_bounds__(256) void init_state(const float* __restrict__ h0,
                                                  const float* __restrict__ c0,
                                                  const float* __restrict__ reset0,
                                                  ushort_t* __restrict__ hbf0,
                                                  float* __restrict__ c0m) {
  const int i = blockIdx.x * 256 + threadIdx.x;
  if (i >= B_SZ * H_SZ) return;
  const float m = 1.0f - reset0[i >> 10];
  hbf0[i] = f2bf(h0[i] * m);
  c0m[i] = c0[i] * m;
}

// ---------------------------------------------------------------------------
// xwbf[m][n] = bf16( bias[n] + sum_k xbf[m][k] * WT[n][k] ),  k in [0,1024)
// (unchanged from R2 — proven; rework targeted for next round)
// ---------------------------------------------------------------------------
__global__ __launch_bounds__(256) void xw_mfma(const ushort_t* __restrict__ xbf,
                                               const ushort_t* __restrict__ WT,
                                               const float* __restrict__ bias,
                                               ushort_t* __restrict__ xwbf) {
  const int lane = threadIdx.x & 63;
  const int wid = threadIdx.x >> 6;
  const int wr = wid >> 1, wc = wid & 1;
  const int m0 = blockIdx.y * 128 + wr * 64;
  const int n0 = blockIdx.x * 128 + wc * 64;
  const int lr = lane & 15;
  const int lk8 = (lane >> 4) * 8;

  const ushort_t* aptr[4];
  const ushort_t* bptr[4];
#pragma unroll
  for (int mi = 0; mi < 4; ++mi)
    aptr[mi] = xbf + (size_t)(m0 + mi * 16 + lr) * D_SZ + lk8;
#pragma unroll
  for (int ni = 0; ni < 4; ++ni)
    bptr[ni] = WT + (size_t)(n0 + ni * 16 + lr) * KW + lk8;

  f32x4 acc[4][4] = {};
  for (int k0 = 0; k0 < D_SZ; k0 += 32) {
    bf16x8 a[4], b[4];
#pragma unroll
    for (int mi = 0; mi < 4; ++mi) {
      a[mi] = *(const bf16x8*)aptr[mi];
      aptr[mi] += 32;
    }
#pragma unroll
    for (int ni = 0; ni < 4; ++ni) {
      b[ni] = *(const bf16x8*)bptr[ni];
      bptr[ni] += 32;
    }
#pragma unroll
    for (int mi = 0; mi < 4; ++mi)
#pragma unroll
      for (int ni = 0; ni < 4; ++ni)
        acc[mi][ni] = __builtin_amdgcn_mfma_f32_16x16x32_bf16(a[mi], b[ni], acc[mi][ni], 0, 0, 0);
  }

  const int rr = (lane >> 4) * 4;
#pragma unroll
  for (int ni = 0; ni < 4; ++ni) {
    const int n = n0 + ni * 16 + lr;
    const float bn = bias[n];
#pragma unroll
    for (int mi = 0; mi < 4; ++mi) {
#pragma unroll
      for (int r = 0; r < 4; ++r) {
        const int m = m0 + mi * 16 + rr + r;
        xwbf[(size_t)m * G4 + n] = f2bf(acc[mi][ni][r] + bn);
      }
    }
  }
}

// ---------------------------------------------------------------------------
// Persistent LSTM recurrence. 256 blocks (1/CU via 146KB LDS) x 256 thr.
// Block: jt = bid&63 (16 j-cols, 4 gates -> 64 N-rows), bt = bid>>6 (32 b-rows).
// Wh slice staged ONCE into LDS (XOR-swizzled). Per step: 4 waves =
// (kh: K-half) x (gh: 32-N-row half); split-K combined via LDS scratch;
// waves 0-1 do elementwise; custom device-scope grid barrier between steps.
// ---------------------------------------------------------------------------
__global__ __launch_bounds__(256, 1) void lstm_persist(
    const ushort_t* __restrict__ hbf0,  // [128][1024] premasked
    const float* __restrict__ c0m,      // [128][1024] premasked
    const ushort_t* __restrict__ xwbf,  // [T][128][4096] bias included
    const ushort_t* __restrict__ WT,    // [4096][2048]
    const float* __restrict__ reset,    // [T][128]
    float* __restrict__ out,            // [T*128][1024] then hT, cT
    ushort_t* __restrict__ hbuf,        // [2][128][1024] premasked bf16
    float* __restrict__ cbuf,           // [2][128][1024] premasked
    uint_t* __restrict__ bar)           // zeroed each launch
{
  __shared__ ushort_t WhL[64 * 1024];   // [nr][k] swizzled, 128 KB
  __shared__ float scratch[2][64][36];  // [kh][nr][row(+pad)] 18 KB

  const int tid = threadIdx.x;
  const int bid = blockIdx.x;
  const int jt = bid & 63;
  const int bt = bid >> 6;
  const int b0 = bt * 32;
  const int lane = tid & 63;
  const int wid = tid >> 6;
  const int kh = wid & 1;
  const int gh = wid >> 1;
  const int lr = lane & 15;
  const int ko = lane >> 4;

  // ---- stage Wh slice (W rows 1024..2048, cols for this block) into LDS ----
  // local row nr = g*16 + jl  ->  WT row n = g*1024 + jt*16 + jl, k = 1024..2048
#pragma unroll 4
  for (int p = 0; p < 32; ++p) {
    const int idx = p * 256 + tid;  // 0..8191
    const int nr = idx >> 7;        // 0..63
    const int oct = idx & 127;      // 16B octet in 2048B row
    const int g = nr >> 4, jl = nr & 15;
    const uint4 v = *(const uint4*)(WT + (size_t)(g * H_SZ + jt * 16 + jl) * KW + H_SZ + oct * 8);
    const int dst = nr * 2048 + ((oct * 16) ^ ((nr & 7) << 4));
    *(uint4*)((char*)WhL + dst) = v;
  }
  __syncthreads();

  const int kbase = kh * 512 + ko * 8;    // element offset in k row
  const int nr0 = gh * 32 + lr;           // B-frag base row (+ni*16)
  const int xr = (nr0 & 7) << 4;          // same for both frags (row+16)
  const int rr = ko * 4;

  float* const hT = out + (size_t)T_STEPS * B_SZ * H_SZ;
  float* const cT = hT + (size_t)B_SZ * H_SZ;

  for (int t = 0; t < T_STEPS; ++t) {
    const ushort_t* hp = (t == 0) ? hbf0 : hbuf + (size_t)((t - 1) & 1) * (B_SZ * H_SZ);
    const float* cp = (t == 0) ? c0m : cbuf + (size_t)((t - 1) & 1) * (B_SZ * H_SZ);

    // ---- GEMM: 32 b-rows x 32 n-cols x K-half per wave ----
    f32x4 acc[2][2] = {};
    const ushort_t* a0p = hp + (size_t)(b0 + lr) * H_SZ + kbase;
    const ushort_t* a1p = hp + (size_t)(b0 + 16 + lr) * H_SZ + kbase;
    const char* wh0 = (const char*)WhL + nr0 * 2048;
    const char* wh1 = (const char*)WhL + (nr0 + 16) * 2048;
#pragma unroll 8
    for (int ks = 0; ks < 16; ++ks) {
      const int kel = ks * 32;
      bf16x8 a0 = *(const bf16x8*)(a0p + kel);
      bf16x8 a1 = *(const bf16x8*)(a1p + kel);
      const int xoff = ((kbase + kel) * 2) ^ xr;
      bf16x8 bf0 = *(const bf16x8*)(wh0 + xoff);
      bf16x8 bf1 = *(const bf16x8*)(wh1 + xoff);
      acc[0][0] = __builtin_amdgcn_mfma_f32_16x16x32_bf16(a0, bf0, acc[0][0], 0, 0, 0);
      acc[1][0] = __builtin_amdgcn_mfma_f32_16x16x32_bf16(a1, bf0, acc[1][0], 0, 0, 0);
      acc[0][1] = __builtin_amdgcn_mfma_f32_16x16x32_bf16(a0, bf1, acc[0][1], 0, 0, 0);
      acc[1][1] = __builtin_amdgcn_mfma_f32_16x16x32_bf16(a1, bf1, acc[1][1], 0, 0, 0);
    }

    // ---- dump partials to scratch ----
#pragma unroll
    for (int mi = 0; mi < 2; ++mi)
#pragma unroll
      for (int ni = 0; ni < 2; ++ni)
        *(f32x4*)&scratch[kh][gh * 32 + ni * 16 + lr][mi * 16 + rr] = acc[mi][ni];
    __syncthreads();

    // ---- elementwise on waves 0-1 ----
    if (wid < 2) {
      const int row = lane & 31;
      const int jgrp = wid * 2 + (lane >> 5);  // 0..3
      const int jl = jgrp * 4;
      const int b = b0 + row;
      const int j = jt * 16 + jl;
      const ushort_t* xp = xwbf + (size_t)t * (B_SZ * G4) + (size_t)b * G4 + j;
      const float4 cv = *(const float4*)(cp + (size_t)b * H_SZ + j);
      const bool last = (t == T_STEPS - 1);
      const float mn = last ? 1.0f : (1.0f - reset[(size_t)(t + 1) * B_SZ + b]);
      float hv[4], hm[4], cm[4];
#pragma unroll
      for (int q = 0; q < 4; ++q) {
        const float gi = scratch[0][jl + q][row] + scratch[1][jl + q][row] + bf2f(xp[q]);
        const float gg = scratch[0][16 + jl + q][row] + scratch[1][16 + jl + q][row] + bf2f(xp[1024 + q]);
        const float gf = scratch[0][32 + jl + q][row] + scratch[1][32 + jl + q][row] + bf2f(xp[2048 + q]);
        const float go = scratch[0][48 + jl + q][row] + scratch[1][48 + jl + q][row] + bf2f(xp[3072 + q]);
        const float c = (&cv.x)[q];
        const float f = sigf(gf + 1.0f);
        const float cn = f * c + sigf(gi) * tanhfast(gg);
        const float hn = sigf(go) * tanhfast(cn);
        hv[q] = hn;
        hm[q] = hn * mn;
        cm[q] = cn * mn;
      }
      *(float4*)(out + (size_t)t * (B_SZ * H_SZ) + (size_t)b * H_SZ + j) = *(float4*)hv;
      if (!last) {
        ushort_t hb[4] = {f2bf(hm[0]), f2bf(hm[1]), f2bf(hm[2]), f2bf(hm[3])};
        *(uint2*)(hbuf + (size_t)(t & 1) * (B_SZ * H_SZ) + (size_t)b * H_SZ + j) = *(uint2*)hb;
        *(float4*)(cbuf + (size_t)(t & 1) * (B_SZ * H_SZ) + (size_t)b * H_SZ + j) = *(float4*)cm;
      } else {
        *(float4*)(hT + (size_t)b * H_SZ + j) = *(float4*)hv;
        *(float4*)(cT + (size_t)b * H_SZ + j) = *(float4*)cm;  // mn==1: unmasked
      }
    }

    // ---- device-wide barrier (not after last step) ----
    if (t != T_STEPS - 1) {
      __syncthreads();
      if (tid == 0) {
        __threadfence();  // release: L2 writeback
        atomicAdd(bar, 1u);
        const uint_t target = (uint_t)(256 * (t + 1));
        for (int spin = 0; spin < 200000; ++spin) {
          if (__hip_atomic_load(bar, __ATOMIC_RELAXED, __HIP_MEMORY_SCOPE_AGENT) >= target) break;
          __builtin_amdgcn_s_sleep(1);
        }
      }
      __syncthreads();
      __threadfence();  // acquire: invalidate L1/L2 before reading fresh h/c
    }
  }
}

extern "C" void kernel_launch(void* const* d_in, const int* in_sizes, int n_in,
                              void* d_out, int out_size, void* d_ws, size_t ws_size,
                              hipStream_t stream) {
  (void)in_sizes; (void)n_in; (void)out_size; (void)ws_size;
  const float* x = (const float*)d_in[0];
  const float* h0 = (const float*)d_in[1];
  const float* c0 = (const float*)d_in[2];
  const float* reset = (const float*)d_in[3];
  const float* W = (const float*)d_in[4];
  const float* bias = (const float*)d_in[5];
  float* out = (float*)d_out;

  const size_t TB = (size_t)T_STEPS * B_SZ;  // 16384
  const size_t SE = (size_t)B_SZ * H_SZ;     // 131072

  // ws layout
  char* p = (char*)d_ws;
  uint_t* bar = (uint_t*)p;               p += 256;
  ushort_t* WT = (ushort_t*)p;            p += (size_t)G4 * KW * 2;
  ushort_t* xbf = (ushort_t*)p;           p += TB * D_SZ * 2;
  ushort_t* xwbf = (ushort_t*)p;          p += TB * G4 * 2;
  ushort_t* hbf0 = (ushort_t*)p;          p += SE * 2;
  ushort_t* hbuf = (ushort_t*)p;          p += 2 * SE * 2;
  float* c0m = (float*)p;                 p += SE * 4;
  float* cbuf = (float*)p;                p += 2 * SE * 4;

  hipMemsetAsync(bar, 0, 256, stream);
  convert_x<<<dim3((int)(TB * D_SZ / 8 / 256)), 256, 0, stream>>>(x, xbf);
  transpose_w<<<dim3(KW / 32, G4 / 32), 256, 0, stream>>>(W, WT);
  init_state<<<dim3((int)((SE + 255) / 256)), 256, 0, stream>>>(h0, c0, reset, hbf0, c0m);
  xw_mfma<<<dim3(G4 / 128, (int)(TB / 128)), 256, 0, stream>>>(xbf, WT, bias, xwbf);

  lstm_persist<<<dim3(256), 256, 0, stream>>>(hbf0, c0m, xwbf, WT, reset, out, hbuf, cbuf, bar);
}

// Round 5
// 1703.508 us; speedup vs baseline: 3.3982x; 3.3982x over previous
//
#include <hip/hip_runtime.h>
#include <math.h>

#define T_STEPS 128
#define B_SZ 128
#define D_SZ 1024
#define H_SZ 1024
#define G4 4096
#define KW 2048  // rows of W = D+H

typedef __attribute__((ext_vector_type(8))) short bf16x8;
typedef __attribute__((ext_vector_type(4))) float f32x4;
typedef unsigned short ushort_t;
typedef unsigned int uint_t;

__device__ __forceinline__ float sigf(float x) { return 1.0f / (1.0f + __expf(-x)); }
__device__ __forceinline__ float tanhfast(float x) { return 1.0f - 2.0f * sigf(-2.0f * x); }

__device__ __forceinline__ ushort_t f2bf(float f) {
  uint_t u = __float_as_uint(f);
  return (ushort_t)((u + 0x7fffu + ((u >> 16) & 1u)) >> 16);
}
__device__ __forceinline__ float bf2f(ushort_t s) {
  return __uint_as_float(((uint_t)s) << 16);
}

#define GLOAD_LDS16(gp, lp)                                                  \
  __builtin_amdgcn_global_load_lds(                                          \
      (const __attribute__((address_space(1))) unsigned int*)(const void*)(gp), \
      (__attribute__((address_space(3))) unsigned int*)(void*)(lp), 16, 0, 0)

// ---------------------------------------------------------------------------
// x fp32 [16384][1024] -> bf16 same layout. 8 elems/thread.
// ---------------------------------------------------------------------------
__global__ __launch_bounds__(256) void convert_x(const float* __restrict__ x,
                                                 ushort_t* __restrict__ xbf) {
  const size_t i8 = ((size_t)blockIdx.x * 256 + threadIdx.x) * 8;
  if (i8 + 8 > (size_t)T_STEPS * B_SZ * D_SZ) return;
  float4 a = *(const float4*)&x[i8];
  float4 b = *(const float4*)&x[i8 + 4];
  ushort_t o[8] = {f2bf(a.x), f2bf(a.y), f2bf(a.z), f2bf(a.w),
                   f2bf(b.x), f2bf(b.y), f2bf(b.z), f2bf(b.w)};
  *(uint4*)&xbf[i8] = *(uint4*)o;
}

// ---------------------------------------------------------------------------
// W fp32 [2048][4096] -> WT bf16 [4096][2048]  (WT[n][k] = W[k][n])
// ---------------------------------------------------------------------------
__global__ __launch_bounds__(256) void transpose_w(const float* __restrict__ W,
                                                   ushort_t* __restrict__ WT) {
  __shared__ float t[32][33];
  const int tx = threadIdx.x & 31;
  const int ty = threadIdx.x >> 5;  // 0..7
  const int k0 = blockIdx.x * 32;
  const int n0 = blockIdx.y * 32;
#pragma unroll
  for (int i = 0; i < 4; ++i)
    t[ty + i * 8][tx] = W[(size_t)(k0 + ty + i * 8) * G4 + n0 + tx];
  __syncthreads();
#pragma unroll
  for (int i = 0; i < 4; ++i)
    WT[(size_t)(n0 + ty + i * 8) * KW + k0 + tx] = f2bf(t[tx][ty + i * 8]);
}

// ---------------------------------------------------------------------------
// hbf0 = bf16(h0 * (1-reset[0])), c0m = c0 * (1-reset[0])
// ---------------------------------------------------------------------------
__global__ __launch_bounds__(256) void init_state(const float* __restrict__ h0,
                                                  const float* __restrict__ c0,
                                                  const float* __restrict__ reset0,
                                                  ushort_t* __restrict__ hbf0,
                                                  float* __restrict__ c0m) {
  const int i = blockIdx.x * 256 + threadIdx.x;
  if (i >= B_SZ * H_SZ) return;
  const float m = 1.0f - reset0[i >> 10];
  hbf0[i] = f2bf(h0[i] * m);
  c0m[i] = c0[i] * m;
}

// ---------------------------------------------------------------------------
// xwbf[m][n] = bf16( bias[n] + sum_k xbf[m][k] * WT[n][k] ), K=1024.
// m97 structure: 128x128 tile, BK=64, 4 waves (2x2), double-buffered LDS,
// global_load_lds w=16, source pre-swizzle (XOR (row&7)<<4), XCD block swizzle.
// ---------------------------------------------------------------------------
__global__ __launch_bounds__(256) void xw_mfma2(const ushort_t* __restrict__ xbf,
                                                const ushort_t* __restrict__ WT,
                                                const float* __restrict__ bias,
                                                ushort_t* __restrict__ xwbf) {
  __shared__ ushort_t Asb[2][128 * 64];  // [buf][row*64+k], 16KB each
  __shared__ ushort_t Bsb[2][128 * 64];

  const int bid = blockIdx.x;                 // 4096 blocks, 4096%8==0
  const int swz = (bid & 7) * 512 + (bid >> 3);
  const int nt = swz >> 7;                    // 0..31
  const int mt = swz & 127;                   // 0..127
  const int m0 = mt * 128, n0 = nt * 128;
  const int tid = threadIdx.x, lane = tid & 63, wid = tid >> 6;
  const int wr = wid >> 1, wc = wid & 1;
  const int lr = lane & 15, ko = lane >> 4;
  const int srow = lane >> 3;                 // 0..7 row within chunk
  const int skb = (lane & 7) * 16;            // 0..112 byte within row-window

  f32x4 acc[4][4] = {};

#define XW_STAGE(buf, kt)                                                      \
  {                                                                            \
    const int k0b = (kt) * 128; /* byte offset of K-window in row */           \
    _Pragma("unroll") for (int i = 0; i < 4; ++i) {                            \
      const int c = wid * 4 + i; /* chunk 0..15 */                             \
      const int row = c * 8 + srow;                                            \
      const int sw = skb ^ ((row & 7) << 4);                                   \
      GLOAD_LDS16((const char*)xbf + (size_t)(m0 + row) * 2048 + k0b + sw,     \
                  (char*)&Asb[buf][0] + c * 1024);                             \
      GLOAD_LDS16((const char*)WT + (size_t)(n0 + row) * 4096 + k0b + sw,      \
                  (char*)&Bsb[buf][0] + c * 1024);                             \
    }                                                                          \
  }

  XW_STAGE(0, 0);
  __syncthreads();
  const int xsw = (lr & 7) << 4;
  for (int kt = 0; kt < 16; ++kt) {
    if (kt + 1 < 16) XW_STAGE((kt + 1) & 1, kt + 1);
    const char* Ab = (const char*)&Asb[kt & 1][0] + (wr * 64 + lr) * 128;
    const char* Bb = (const char*)&Bsb[kt & 1][0] + (wc * 64 + lr) * 128;
#pragma unroll
    for (int ks = 0; ks < 2; ++ks) {
      const int kb = (ks * 64 + ko * 16) ^ xsw;
      bf16x8 a[4], b[4];
#pragma unroll
      for (int mi = 0; mi < 4; ++mi) a[mi] = *(const bf16x8*)(Ab + mi * 2048 + kb);
#pragma unroll
      for (int ni = 0; ni < 4; ++ni) b[ni] = *(const bf16x8*)(Bb + ni * 2048 + kb);
#pragma unroll
      for (int mi = 0; mi < 4; ++mi)
#pragma unroll
        for (int ni = 0; ni < 4; ++ni)
          acc[mi][ni] = __builtin_amdgcn_mfma_f32_16x16x32_bf16(a[mi], b[ni], acc[mi][ni], 0, 0, 0);
    }
    __syncthreads();
  }

  const int rr = ko * 4;
#pragma unroll
  for (int ni = 0; ni < 4; ++ni) {
    const int n = n0 + wc * 64 + ni * 16 + lr;
    const float bn = bias[n];
#pragma unroll
    for (int mi = 0; mi < 4; ++mi) {
#pragma unroll
      for (int r = 0; r < 4; ++r) {
        const int m = m0 + wr * 64 + mi * 16 + rr + r;
        xwbf[(size_t)m * G4 + n] = f2bf(acc[mi][ni][r] + bn);
      }
    }
  }
}

// ---------------------------------------------------------------------------
// One LSTM step. Grid (64 j-tiles, 4 b-tiles) x 512 thr = 8 waves.
// Wave (wm 0..1, g 0..3): out rows [b0+wm*16,+16) x N-rows g*1024+jt*16+[0,16).
// h-tile (32 rows x 1024) staged via global_load_lds w=16 with src pre-swizzle;
// Wh direct global (k in [1024,2048) of WT rows!). Gate combine via LDS
// scratch; fused elementwise.
// ---------------------------------------------------------------------------
__global__ __launch_bounds__(512) void lstm_step_v2(
    const ushort_t* __restrict__ hbf_prev,  // [128][1024] premasked bf16
    const float* __restrict__ c_prev,       // [128][1024] premasked
    const ushort_t* __restrict__ xwbf_t,    // [128][4096] bias included
    const ushort_t* __restrict__ WT,        // [4096][2048]
    const float* __restrict__ reset_next,   // [128] or null (last step)
    float* __restrict__ h_out,              // [128][1024]
    ushort_t* __restrict__ hbf_next,        // [128][1024] or null
    float* __restrict__ c_out)              // [128][1024]
{
  __shared__ ushort_t Ah[32 * 1024];  // [row][k] swizzled, 64 KB
  __shared__ float sc[8][16][17];     // [wid = wm*4+g][row16][col16], 8.7 KB

  const int tid = threadIdx.x;
  const int lane = tid & 63;
  const int wid = tid >> 6;   // 0..7
  const int g = wid & 3;
  const int wm = wid >> 2;
  const int jt = blockIdx.x;  // 0..63
  const int bt = blockIdx.y;  // 0..3
  const int b0 = bt * 32;
  const int lr = lane & 15;
  const int ko = lane >> 4;   // 0..3

  // ---- stage h rows [b0,b0+32) -> LDS (64 chunks of 1KB, 8 per wave) ----
#pragma unroll
  for (int i = 0; i < 8; ++i) {
    const int c = wid * 8 + i;            // 0..63
    const int row = c >> 1;
    const int half = (c & 1) * 1024;      // byte offset in 2048B row
    const int kb = half + lane * 16;
    const int src = kb ^ ((row & 7) << 4);
    GLOAD_LDS16((const char*)(hbf_prev + (size_t)(b0 + row) * H_SZ) + src,
                (char*)Ah + row * 2048 + half);
  }
  __syncthreads();

  // ---- GEMM: 16x16 out per wave, K=1024 (Wh half: +H_SZ element offset) ----
  const char* arow = (const char*)Ah + (wm * 16 + lr) * 2048;
  const int aswz = (lr & 7) << 4;
  const char* bp = (const char*)(WT + (size_t)(g * H_SZ + jt * 16 + lr) * KW + H_SZ);
  f32x4 acc = {};
#pragma unroll 8
  for (int ks = 0; ks < 32; ++ks) {
    const int kb = ks * 64 + ko * 16;
    bf16x8 a = *(const bf16x8*)(arow + (kb ^ aswz));
    bf16x8 b = *(const bf16x8*)(bp + kb);
    acc = __builtin_amdgcn_mfma_f32_16x16x32_bf16(a, b, acc, 0, 0, 0);
  }

#pragma unroll
  for (int r = 0; r < 4; ++r) sc[wid][ko * 4 + r][lr] = acc[r];
  __syncthreads();

  // ---- fused elementwise: 512 threads -> 32 rows x 16 cols ----
  const int row = tid >> 4;   // 0..31
  const int col = tid & 15;
  const int b = b0 + row;
  const int j = jt * 16 + col;
  const int w0 = (row >> 4) * 4;
  const int r16 = row & 15;
  const size_t xo = (size_t)b * G4 + j;
  const float gi = sc[w0 + 0][r16][col] + bf2f(xwbf_t[xo]);
  const float gg = sc[w0 + 1][r16][col] + bf2f(xwbf_t[xo + H_SZ]);
  const float gf = sc[w0 + 2][r16][col] + bf2f(xwbf_t[xo + 2 * H_SZ]);
  const float go = sc[w0 + 3][r16][col] + bf2f(xwbf_t[xo + 3 * H_SZ]);
  const size_t so = (size_t)b * H_SZ + j;
  const float c = c_prev[so];
  const float f = sigf(gf + 1.0f);
  const float cn = f * c + sigf(gi) * tanhfast(gg);
  const float hn = sigf(go) * tanhfast(cn);
  h_out[so] = hn;
  if (hbf_next) {
    const float mn = 1.0f - reset_next[b];
    hbf_next[so] = f2bf(hn * mn);
    c_out[so] = cn * mn;
  } else {
    c_out[so] = cn;  // last step: cT unmasked
  }
}

__global__ __launch_bounds__(256) void copy_hT(const float* __restrict__ src,
                                               float* __restrict__ dst) {
  const int i = blockIdx.x * 256 + threadIdx.x;
  if (i < B_SZ * H_SZ) dst[i] = src[i];
}

extern "C" void kernel_launch(void* const* d_in, const int* in_sizes, int n_in,
                              void* d_out, int out_size, void* d_ws, size_t ws_size,
                              hipStream_t stream) {
  (void)in_sizes; (void)n_in; (void)out_size; (void)ws_size;
  const float* x = (const float*)d_in[0];
  const float* h0 = (const float*)d_in[1];
  const float* c0 = (const float*)d_in[2];
  const float* reset = (const float*)d_in[3];
  const float* W = (const float*)d_in[4];
  const float* bias = (const float*)d_in[5];
  float* out = (float*)d_out;

  const size_t TB = (size_t)T_STEPS * B_SZ;  // 16384
  const size_t SE = (size_t)B_SZ * H_SZ;     // 131072

  // ws layout
  char* p = (char*)d_ws;
  ushort_t* WT = (ushort_t*)p;            p += (size_t)G4 * KW * 2;
  ushort_t* xbf = (ushort_t*)p;           p += TB * D_SZ * 2;
  ushort_t* xwbf = (ushort_t*)p;          p += TB * G4 * 2;
  ushort_t* hbf0 = (ushort_t*)p;          p += SE * 2;
  ushort_t* hbuf = (ushort_t*)p;          p += 2 * SE * 2;
  float* c0m = (float*)p;                 p += SE * 4;
  float* cbuf = (float*)p;                p += 2 * SE * 4;

  convert_x<<<dim3((int)(TB * D_SZ / 8 / 256)), 256, 0, stream>>>(x, xbf);
  transpose_w<<<dim3(KW / 32, G4 / 32), 256, 0, stream>>>(W, WT);
  init_state<<<dim3((int)((SE + 255) / 256)), 256, 0, stream>>>(h0, c0, reset, hbf0, c0m);
  xw_mfma2<<<dim3(4096), 256, 0, stream>>>(xbf, WT, bias, xwbf);

  float* hT = out + TB * H_SZ;
  float* cT = hT + SE;

  for (int t = 0; t < T_STEPS; ++t) {
    const ushort_t* hp = (t == 0) ? hbf0 : hbuf + (size_t)((t - 1) & 1) * SE;
    const float* cp = (t == 0) ? c0m : cbuf + (size_t)((t - 1) & 1) * SE;
    float* ho = out + (size_t)t * SE;
    const bool last = (t == T_STEPS - 1);
    ushort_t* hn = last ? nullptr : hbuf + (size_t)(t & 1) * SE;
    float* cn = last ? cT : cbuf + (size_t)(t & 1) * SE;
    const float* rn = last ? nullptr : (reset + (size_t)(t + 1) * B_SZ);
    lstm_step_v2<<<dim3(64, 4), 512, 0, stream>>>(
        hp, cp, xwbf + (size_t)t * B_SZ * G4, WT, rn, ho, hn, cn);
  }

  copy_hT<<<dim3((int)((SE + 255) / 256)), 256, 0, stream>>>(
      out + (TB - B_SZ) * H_SZ, hT);
}

// Round 6
// 1603.839 us; speedup vs baseline: 3.6093x; 1.0621x over previous
//
#include <hip/hip_runtime.h>
#include <math.h>

#define T_STEPS 128
#define B_SZ 128
#define D_SZ 1024
#define H_SZ 1024
#define G4 4096
#define KW 2048  // rows of W = D+H

typedef __attribute__((ext_vector_type(8))) short bf16x8;
typedef __attribute__((ext_vector_type(4))) float f32x4;
typedef unsigned short ushort_t;
typedef unsigned int uint_t;

__device__ __forceinline__ float sigf(float x) { return 1.0f / (1.0f + __expf(-x)); }
__device__ __forceinline__ float tanhfast(float x) { return 1.0f - 2.0f * sigf(-2.0f * x); }

__device__ __forceinline__ ushort_t f2bf(float f) {
  uint_t u = __float_as_uint(f);
  return (ushort_t)((u + 0x7fffu + ((u >> 16) & 1u)) >> 16);
}
__device__ __forceinline__ float bf2f(ushort_t s) {
  return __uint_as_float(((uint_t)s) << 16);
}

#define GLOAD_LDS16(gp, lp)                                                  \
  __builtin_amdgcn_global_load_lds(                                          \
      (const __attribute__((address_space(1))) unsigned int*)(const void*)(gp), \
      (__attribute__((address_space(3))) unsigned int*)(void*)(lp), 16, 0, 0)

// ---------------------------------------------------------------------------
// x fp32 [16384][1024] -> bf16 same layout. 8 elems/thread.
// ---------------------------------------------------------------------------
__global__ __launch_bounds__(256) void convert_x(const float* __restrict__ x,
                                                 ushort_t* __restrict__ xbf) {
  const size_t i8 = ((size_t)blockIdx.x * 256 + threadIdx.x) * 8;
  if (i8 + 8 > (size_t)T_STEPS * B_SZ * D_SZ) return;
  float4 a = *(const float4*)&x[i8];
  float4 b = *(const float4*)&x[i8 + 4];
  ushort_t o[8] = {f2bf(a.x), f2bf(a.y), f2bf(a.z), f2bf(a.w),
                   f2bf(b.x), f2bf(b.y), f2bf(b.z), f2bf(b.w)};
  *(uint4*)&xbf[i8] = *(uint4*)o;
}

// ---------------------------------------------------------------------------
// W fp32 [2048][4096] -> WT bf16 [4096][2048]  (WT[n][k] = W[k][n])
// ---------------------------------------------------------------------------
__global__ __launch_bounds__(256) void transpose_w(const float* __restrict__ W,
                                                   ushort_t* __restrict__ WT) {
  __shared__ float t[32][33];
  const int tx = threadIdx.x & 31;
  const int ty = threadIdx.x >> 5;  // 0..7
  const int k0 = blockIdx.x * 32;
  const int n0 = blockIdx.y * 32;
#pragma unroll
  for (int i = 0; i < 4; ++i)
    t[ty + i * 8][tx] = W[(size_t)(k0 + ty + i * 8) * G4 + n0 + tx];
  __syncthreads();
#pragma unroll
  for (int i = 0; i < 4; ++i)
    WT[(size_t)(n0 + ty + i * 8) * KW + k0 + tx] = f2bf(t[tx][ty + i * 8]);
}

// ---------------------------------------------------------------------------
// hbf0 = bf16(h0 * (1-reset[0])), c0m = c0 * (1-reset[0])
// ---------------------------------------------------------------------------
__global__ __launch_bounds__(256) void init_state(const float* __restrict__ h0,
                                                  const float* __restrict__ c0,
                                                  const float* __restrict__ reset0,
                                                  ushort_t* __restrict__ hbf0,
                                                  float* __restrict__ c0m) {
  const int i = blockIdx.x * 256 + threadIdx.x;
  if (i >= B_SZ * H_SZ) return;
  const float m = 1.0f - reset0[i >> 10];
  hbf0[i] = f2bf(h0[i] * m);
  c0m[i] = c0[i] * m;
}

// ---------------------------------------------------------------------------
// Gate pre-activation from x:  value = bias[n] + sum_k xbf[m][k]*WT[n][k].
// Output layout (step-kernel friendly):
//   xwg[ ((t*8 + bt)*64 + jt)*1024 + g*256 + r*16 + c ]
// where m = t*128 + bt*16 + r,  n = g*1024 + jt*16 + c.
// m97 structure: 128x128 tile, BK=64, 4 waves (2x2), double-buffered LDS,
// global_load_lds w=16, source pre-swizzle, XCD block swizzle.
// ---------------------------------------------------------------------------
__global__ __launch_bounds__(256) void xw_mfma2(const ushort_t* __restrict__ xbf,
                                                const ushort_t* __restrict__ WT,
                                                const float* __restrict__ bias,
                                                ushort_t* __restrict__ xwg) {
  __shared__ ushort_t Asb[2][128 * 64];  // [buf][row*64+k], 16KB each
  __shared__ ushort_t Bsb[2][128 * 64];

  const int bid = blockIdx.x;                 // 4096 blocks, 4096%8==0
  const int swz = (bid & 7) * 512 + (bid >> 3);
  const int nt = swz >> 7;                    // 0..31
  const int mt = swz & 127;                   // 0..127
  const int m0 = mt * 128, n0 = nt * 128;
  const int tid = threadIdx.x, lane = tid & 63, wid = tid >> 6;
  const int wr = wid >> 1, wc = wid & 1;
  const int lr = lane & 15, ko = lane >> 4;
  const int srow = lane >> 3;                 // 0..7 row within chunk
  const int skb = (lane & 7) * 16;            // 0..112 byte within row-window

  f32x4 acc[4][4] = {};

#define XW_STAGE(buf, kt)                                                      \
  {                                                                            \
    const int k0b = (kt) * 128; /* byte offset of K-window in row */           \
    _Pragma("unroll") for (int i = 0; i < 4; ++i) {                            \
      const int c = wid * 4 + i; /* chunk 0..15 */                             \
      const int row = c * 8 + srow;                                            \
      const int sw = skb ^ ((row & 7) << 4);                                   \
      GLOAD_LDS16((const char*)xbf + (size_t)(m0 + row) * 2048 + k0b + sw,     \
                  (char*)&Asb[buf][0] + c * 1024);                             \
      GLOAD_LDS16((const char*)WT + (size_t)(n0 + row) * 4096 + k0b + sw,      \
                  (char*)&Bsb[buf][0] + c * 1024);                             \
    }                                                                          \
  }

  XW_STAGE(0, 0);
  __syncthreads();
  const int xsw = (lr & 7) << 4;
  for (int kt = 0; kt < 16; ++kt) {
    if (kt + 1 < 16) XW_STAGE((kt + 1) & 1, kt + 1);
    const char* Ab = (const char*)&Asb[kt & 1][0] + (wr * 64 + lr) * 128;
    const char* Bb = (const char*)&Bsb[kt & 1][0] + (wc * 64 + lr) * 128;
#pragma unroll
    for (int ks = 0; ks < 2; ++ks) {
      const int kb = (ks * 64 + ko * 16) ^ xsw;
      bf16x8 a[4], b[4];
#pragma unroll
      for (int mi = 0; mi < 4; ++mi) a[mi] = *(const bf16x8*)(Ab + mi * 2048 + kb);
#pragma unroll
      for (int ni = 0; ni < 4; ++ni) b[ni] = *(const bf16x8*)(Bb + ni * 2048 + kb);
#pragma unroll
      for (int mi = 0; mi < 4; ++mi)
#pragma unroll
        for (int ni = 0; ni < 4; ++ni)
          acc[mi][ni] = __builtin_amdgcn_mfma_f32_16x16x32_bf16(a[mi], b[ni], acc[mi][ni], 0, 0, 0);
    }
    __syncthreads();
  }

  const int rr = ko * 4;
  const int tt = m0 >> 7;  // = mt (m-offsets within tile < 128)
#pragma unroll
  for (int ni = 0; ni < 4; ++ni) {
    const int nb = n0 + wc * 64 + ni * 16;   // col = nb + lr
    const int gidx = nb >> 10;
    const int jtn = (nb & 1023) >> 4;
    const float bn = bias[nb + lr];
#pragma unroll
    for (int mi = 0; mi < 4; ++mi) {
      const int btm = ((wr * 64 + mi * 16) >> 4);  // bt within this t
      ushort_t* dst = xwg + (((size_t)tt * 8 + btm) * 64 + jtn) * 1024 + gidx * 256 + lr;
#pragma unroll
      for (int r = 0; r < 4; ++r)
        dst[(rr + r) * 16] = f2bf(acc[mi][ni][r] + bn);
    }
  }
}

// ---------------------------------------------------------------------------
// One LSTM step. Grid (64 jt, 8 bt) = 512 blocks x 256 thr = 4 waves.
// Wave = gate g. Block output: rows [bt*16,+16) x cols [jt*16,+16).
// 2 blocks/CU -> phase overlap. Wh slice per XCD (jt%8 fixed) = 1MB, L2-hot.
// Pipelining: elementwise operands + 8-deep Wh register ring issued before
// the staging barrier; K-loop refills ring 8 ahead (static idx, full unroll).
// ---------------------------------------------------------------------------
__global__ __launch_bounds__(256) void lstm_step_v3(
    const ushort_t* __restrict__ hbf_prev,  // [128][1024] premasked bf16
    const float* __restrict__ c_prev,       // [128][1024] premasked
    const ushort_t* __restrict__ xwg_t,     // [8][64][4][16][16] bias included
    const ushort_t* __restrict__ WT,        // [4096][2048]
    const float* __restrict__ reset_next,   // [128] or null (last step)
    float* __restrict__ h_out,              // [128][1024]
    ushort_t* __restrict__ hbf_next,        // [128][1024] or null
    float* __restrict__ c_out)              // [128][1024]
{
  __shared__ ushort_t Ah[16 * 1024];  // [row][k] swizzled, 32 KB
  __shared__ float sc[4][16][17];     // [gate][brow][jcol], 4.4 KB

  const int tid = threadIdx.x;
  const int lane = tid & 63;
  const int g = tid >> 6;      // wave id = gate 0..3
  const int jt = blockIdx.x;   // 0..63
  const int bt = blockIdx.y;   // 0..7
  const int b0 = bt * 16;
  const int lr = lane & 15;
  const int ko = lane >> 4;    // 0..3

  // ---- early: elementwise operands (hidden under staging+GEMM) ----
  const int erow = tid >> 4;   // 0..15
  const int ecol = tid & 15;
  const int eb = b0 + erow;
  const int ej = jt * 16 + ecol;
  const size_t so = (size_t)eb * H_SZ + ej;
  const float cv = c_prev[so];
  const ushort_t* xwp = xwg_t + ((size_t)bt * 64 + jt) * 1024 + erow * 16 + ecol;
  const ushort_t xw0 = xwp[0];
  const ushort_t xw1 = xwp[256];
  const ushort_t xw2 = xwp[512];
  const ushort_t xw3 = xwp[768];
  const float mn = reset_next ? (1.0f - reset_next[eb]) : 1.0f;

  // ---- stage h rows [b0,b0+16) -> LDS (32 chunks of 1KB, 8 per wave) ----
#pragma unroll
  for (int i = 0; i < 8; ++i) {
    const int c = g * 8 + i;            // 0..31
    const int row = c >> 1;
    const int half = (c & 1) * 1024;    // byte offset in 2048B row
    const int kb = half + lane * 16;
    const int src = kb ^ ((row & 7) << 4);
    GLOAD_LDS16((const char*)(hbf_prev + (size_t)(b0 + row) * H_SZ) + src,
                (char*)Ah + row * 2048 + half);
  }

  // ---- prefetch first 8 Wh fragments into a register ring ----
  const char* bp = (const char*)(WT + (size_t)(g * H_SZ + jt * 16 + lr) * KW + H_SZ) + ko * 16;
  bf16x8 breg[8];
#pragma unroll
  for (int p = 0; p < 8; ++p) breg[p] = *(const bf16x8*)(bp + p * 64);

  __syncthreads();

  // ---- GEMM: 16x16 out per wave, K=1024 over Wh ----
  const char* arow = (const char*)Ah + lr * 2048;
  const int aswz = (lr & 7) << 4;
  f32x4 acc = {};
#pragma unroll
  for (int ks = 0; ks < 32; ++ks) {
    bf16x8 b = breg[ks & 7];
    if (ks < 24) breg[ks & 7] = *(const bf16x8*)(bp + (ks + 8) * 64);
    bf16x8 a = *(const bf16x8*)(arow + ((ks * 64 + ko * 16) ^ aswz));
    acc = __builtin_amdgcn_mfma_f32_16x16x32_bf16(a, b, acc, 0, 0, 0);
  }

#pragma unroll
  for (int r = 0; r < 4; ++r) sc[g][ko * 4 + r][lr] = acc[r];
  __syncthreads();

  // ---- fused elementwise: 256 threads -> 16 rows x 16 cols ----
  const float gi = sc[0][erow][ecol] + bf2f(xw0);
  const float gg = sc[1][erow][ecol] + bf2f(xw1);
  const float gf = sc[2][erow][ecol] + bf2f(xw2);
  const float go = sc[3][erow][ecol] + bf2f(xw3);
  const float f = sigf(gf + 1.0f);
  const float cn = f * cv + sigf(gi) * tanhfast(gg);
  const float hn = sigf(go) * tanhfast(cn);
  h_out[so] = hn;
  if (hbf_next) {
    hbf_next[so] = f2bf(hn * mn);
    c_out[so] = cn * mn;
  } else {
    c_out[so] = cn;  // last step: cT unmasked
  }
}

__global__ __launch_bounds__(256) void copy_hT(const float* __restrict__ src,
                                               float* __restrict__ dst) {
  const int i = blockIdx.x * 256 + threadIdx.x;
  if (i < B_SZ * H_SZ) dst[i] = src[i];
}

extern "C" void kernel_launch(void* const* d_in, const int* in_sizes, int n_in,
                              void* d_out, int out_size, void* d_ws, size_t ws_size,
                              hipStream_t stream) {
  (void)in_sizes; (void)n_in; (void)out_size; (void)ws_size;
  const float* x = (const float*)d_in[0];
  const float* h0 = (const float*)d_in[1];
  const float* c0 = (const float*)d_in[2];
  const float* reset = (const float*)d_in[3];
  const float* W = (const float*)d_in[4];
  const float* bias = (const float*)d_in[5];
  float* out = (float*)d_out;

  const size_t TB = (size_t)T_STEPS * B_SZ;  // 16384
  const size_t SE = (size_t)B_SZ * H_SZ;     // 131072

  // ws layout
  char* p = (char*)d_ws;
  ushort_t* WT = (ushort_t*)p;            p += (size_t)G4 * KW * 2;
  ushort_t* xbf = (ushort_t*)p;           p += TB * D_SZ * 2;
  ushort_t* xwg = (ushort_t*)p;           p += TB * G4 * 2;
  ushort_t* hbf0 = (ushort_t*)p;          p += SE * 2;
  ushort_t* hbuf = (ushort_t*)p;          p += 2 * SE * 2;
  float* c0m = (float*)p;                 p += SE * 4;
  float* cbuf = (float*)p;                p += 2 * SE * 4;

  convert_x<<<dim3((int)(TB * D_SZ / 8 / 256)), 256, 0, stream>>>(x, xbf);
  transpose_w<<<dim3(KW / 32, G4 / 32), 256, 0, stream>>>(W, WT);
  init_state<<<dim3((int)((SE + 255) / 256)), 256, 0, stream>>>(h0, c0, reset, hbf0, c0m);
  xw_mfma2<<<dim3(4096), 256, 0, stream>>>(xbf, WT, bias, xwg);

  float* hT = out + TB * H_SZ;
  float* cT = hT + SE;

  for (int t = 0; t < T_STEPS; ++t) {
    const ushort_t* hp = (t == 0) ? hbf0 : hbuf + (size_t)((t - 1) & 1) * SE;
    const float* cp = (t == 0) ? c0m : cbuf + (size_t)((t - 1) & 1) * SE;
    float* ho = out + (size_t)t * SE;
    const bool last = (t == T_STEPS - 1);
    ushort_t* hn = last ? nullptr : hbuf + (size_t)(t & 1) * SE;
    float* cn = last ? cT : cbuf + (size_t)(t & 1) * SE;
    const float* rn = last ? nullptr : (reset + (size_t)(t + 1) * B_SZ);
    lstm_step_v3<<<dim3(64, 8), 256, 0, stream>>>(
        hp, cp, xwg + (size_t)t * B_SZ * G4, WT, rn, ho, hn, cn);
  }

  copy_hT<<<dim3((int)((SE + 255) / 256)), 256, 0, stream>>>(
      out + (TB - B_SZ) * H_SZ, hT);
}

// Round 7
// 1000.094 us; speedup vs baseline: 5.7883x; 1.6037x over previous
//
#include <hip/hip_runtime.h>
#include <math.h>

#define T_STEPS 128
#define B_SZ 128
#define D_SZ 1024
#define H_SZ 1024
#define G4 4096
#define KW 2048  // rows of W = D+H

typedef __attribute__((ext_vector_type(8))) short bf16x8;
typedef __attribute__((ext_vector_type(4))) float f32x4;
typedef unsigned short ushort_t;
typedef unsigned int uint_t;
typedef unsigned long long ull_t;

__device__ __forceinline__ float sigf(float x) { return 1.0f / (1.0f + __expf(-x)); }
__device__ __forceinline__ float tanhfast(float x) { return 1.0f - 2.0f * sigf(-2.0f * x); }

__device__ __forceinline__ ushort_t f2bf(float f) {
  uint_t u = __float_as_uint(f);
  return (ushort_t)((u + 0x7fffu + ((u >> 16) & 1u)) >> 16);
}
__device__ __forceinline__ float bf2f(ushort_t s) {
  return __uint_as_float(((uint_t)s) << 16);
}

#define GLOAD_LDS16(gp, lp)                                                  \
  __builtin_amdgcn_global_load_lds(                                          \
      (const __attribute__((address_space(1))) unsigned int*)(const void*)(gp), \
      (__attribute__((address_space(3))) unsigned int*)(void*)(lp), 16, 0, 0)

// ---------------------------------------------------------------------------
// x fp32 [16384][1024] -> bf16 same layout. 8 elems/thread.
// ---------------------------------------------------------------------------
__global__ __launch_bounds__(256) void convert_x(const float* __restrict__ x,
                                                 ushort_t* __restrict__ xbf) {
  const size_t i8 = ((size_t)blockIdx.x * 256 + threadIdx.x) * 8;
  if (i8 + 8 > (size_t)T_STEPS * B_SZ * D_SZ) return;
  float4 a = *(const float4*)&x[i8];
  float4 b = *(const float4*)&x[i8 + 4];
  ushort_t o[8] = {f2bf(a.x), f2bf(a.y), f2bf(a.z), f2bf(a.w),
                   f2bf(b.x), f2bf(b.y), f2bf(b.z), f2bf(b.w)};
  *(uint4*)&xbf[i8] = *(uint4*)o;
}

// ---------------------------------------------------------------------------
// W fp32 [2048][4096] -> WT bf16 [4096][2048]  (WT[n][k] = W[k][n])
// ---------------------------------------------------------------------------
__global__ __launch_bounds__(256) void transpose_w(const float* __restrict__ W,
                                                   ushort_t* __restrict__ WT) {
  __shared__ float t[32][33];
  const int tx = threadIdx.x & 31;
  const int ty = threadIdx.x >> 5;  // 0..7
  const int k0 = blockIdx.x * 32;
  const int n0 = blockIdx.y * 32;
#pragma unroll
  for (int i = 0; i < 4; ++i)
    t[ty + i * 8][tx] = W[(size_t)(k0 + ty + i * 8) * G4 + n0 + tx];
  __syncthreads();
#pragma unroll
  for (int i = 0; i < 4; ++i)
    WT[(size_t)(n0 + ty + i * 8) * KW + k0 + tx] = f2bf(t[tx][ty + i * 8]);
}

// ---------------------------------------------------------------------------
// hbf0 = bf16(h0 * (1-reset[0]))
// ---------------------------------------------------------------------------
__global__ __launch_bounds__(256) void init_state(const float* __restrict__ h0,
                                                  const float* __restrict__ reset0,
                                                  ushort_t* __restrict__ hbf0) {
  const int i = blockIdx.x * 256 + threadIdx.x;
  if (i >= B_SZ * H_SZ) return;
  hbf0[i] = f2bf(h0[i] * (1.0f - reset0[i >> 10]));
}

// ---------------------------------------------------------------------------
// Gate pre-activation from x:  val = bias[n] + sum_k xbf[m][k]*WT[n][k].
// Output layout for persist blocks: element idx =
//   ((((t*4 + btp)*64 + jt)*512) + r32*16 + c)*4 + g
// where m = t*128 + btp*32 + r32, n = g*1024 + jt*16 + c.
// ---------------------------------------------------------------------------
__global__ __launch_bounds__(256) void xw_mfma2(const ushort_t* __restrict__ xbf,
                                                const ushort_t* __restrict__ WT,
                                                const float* __restrict__ bias,
                                                ushort_t* __restrict__ xwg) {
  __shared__ ushort_t Asb[2][128 * 64];  // [buf][row*64+k], 16KB each
  __shared__ ushort_t Bsb[2][128 * 64];

  const int bid = blockIdx.x;                 // 4096 blocks, 4096%8==0
  const int swz = (bid & 7) * 512 + (bid >> 3);
  const int nt = swz >> 7;                    // 0..31
  const int mt = swz & 127;                   // 0..127
  const int m0 = mt * 128, n0 = nt * 128;
  const int tid = threadIdx.x, lane = tid & 63, wid = tid >> 6;
  const int wr = wid >> 1, wc = wid & 1;
  const int lr = lane & 15, ko = lane >> 4;
  const int srow = lane >> 3;                 // 0..7 row within chunk
  const int skb = (lane & 7) * 16;            // byte within row-window

  f32x4 acc[4][4] = {};

#define XW_STAGE(buf, kt)                                                      \
  {                                                                            \
    const int k0b = (kt) * 128;                                                \
    _Pragma("unroll") for (int i = 0; i < 4; ++i) {                            \
      const int c = wid * 4 + i;                                               \
      const int row = c * 8 + srow;                                            \
      const int sw = skb ^ ((row & 7) << 4);                                   \
      GLOAD_LDS16((const char*)xbf + (size_t)(m0 + row) * 2048 + k0b + sw,     \
                  (char*)&Asb[buf][0] + c * 1024);                             \
      GLOAD_LDS16((const char*)WT + (size_t)(n0 + row) * 4096 + k0b + sw,      \
                  (char*)&Bsb[buf][0] + c * 1024);                             \
    }                                                                          \
  }

  XW_STAGE(0, 0);
  __syncthreads();
  const int xsw = (lr & 7) << 4;
  for (int kt = 0; kt < 16; ++kt) {
    if (kt + 1 < 16) XW_STAGE((kt + 1) & 1, kt + 1);
    const char* Ab = (const char*)&Asb[kt & 1][0] + (wr * 64 + lr) * 128;
    const char* Bb = (const char*)&Bsb[kt & 1][0] + (wc * 64 + lr) * 128;
#pragma unroll
    for (int ks = 0; ks < 2; ++ks) {
      const int kb = (ks * 64 + ko * 16) ^ xsw;
      bf16x8 a[4], b[4];
#pragma unroll
      for (int mi = 0; mi < 4; ++mi) a[mi] = *(const bf16x8*)(Ab + mi * 2048 + kb);
#pragma unroll
      for (int ni = 0; ni < 4; ++ni) b[ni] = *(const bf16x8*)(Bb + ni * 2048 + kb);
#pragma unroll
      for (int mi = 0; mi < 4; ++mi)
#pragma unroll
        for (int ni = 0; ni < 4; ++ni)
          acc[mi][ni] = __builtin_amdgcn_mfma_f32_16x16x32_bf16(a[mi], b[ni], acc[mi][ni], 0, 0, 0);
    }
    __syncthreads();
  }

  const int rr = ko * 4;
#pragma unroll
  for (int ni = 0; ni < 4; ++ni) {
    const int n = n0 + wc * 64 + ni * 16 + lr;
    const int gg = n >> 10;
    const int jj = n & 1023;
    const size_t jbase = ((size_t)(jj >> 4) * 512 + (jj & 15) * 0) ;  // jt part folded below
    const float bn = bias[n];
#pragma unroll
    for (int mi = 0; mi < 4; ++mi) {
#pragma unroll
      for (int r = 0; r < 4; ++r) {
        const int m = m0 + wr * 64 + mi * 16 + rr + r;
        const int tt = m >> 7;
        const int btp = (m & 127) >> 5;
        const int r32 = m & 31;
        xwg[((((size_t)tt * 4 + btp) * 64 + (jj >> 4)) * 512 + r32 * 16 + (jj & 15)) * 4 + gg] =
            f2bf(acc[mi][ni][r] + bn);
      }
    }
    (void)jbase;
  }
}

// ---------------------------------------------------------------------------
// Persistent LSTM recurrence. 256 blocks (1/CU, forced by 139KB LDS) x 512thr.
// Block owns (jt = bid&63, btp = bid>>6 -> 32 b-rows). Wave (g = wid&3,
// mh = wid>>2) computes gate g for rows [b0+mh*16,+16) x cols [jt*16,+16).
// Wh resident forever: k[1024,1536) in LDS (swizzled), k[1536,2048) in 64
// VGPRs/thread. c resident in 1 reg/thread. Per step: h via L3-coherent
// relaxed-agent atomics (sc0/sc1, NO fences -> L2 stays warm), fence-free
// two-level grid barrier (16x16 tree + gen flag).
// ---------------------------------------------------------------------------
__global__ __launch_bounds__(512) void lstm_persist2(
    const ushort_t* __restrict__ hbf0,  // [128][1024] premasked bf16
    const float* __restrict__ c0,       // [128][1024] raw
    const float* __restrict__ reset,    // [T][128]
    const ushort_t* __restrict__ xwg,   // relayout, bias included
    const ushort_t* __restrict__ WT,    // [4096][2048]
    float* __restrict__ out,            // [T*128][1024] then hT, cT
    ushort_t* __restrict__ hbuf,        // [2][128][1024] premasked bf16
    uint_t* __restrict__ bar)           // zeroed each launch
{
  __shared__ ushort_t WhL[64 * 512];   // [nr][k half], swizzled, 64 KB
  __shared__ ushort_t Ah[32 * 1024];   // [row][k], swizzled, 64 KB
  __shared__ float sc[2][4][16][17];   // [mh][g][brow][jcol], 8.7 KB

  const int tid = threadIdx.x;
  const int bid = blockIdx.x;   // 0..255
  const int jt = bid & 63;
  const int btp = bid >> 6;     // 0..3
  const int b0 = btp * 32;
  const int lane = tid & 63;
  const int wid = tid >> 6;     // 0..7
  const int g = wid & 3;
  const int mh = wid >> 2;
  const int lr = lane & 15;
  const int ko = lane >> 4;
  const int grp = bid >> 4;     // 0..15

  // ---- stage Wh k in [1024,1536) into LDS (once) ----
  for (int p = 0; p < 8; ++p) {
    const int id = p * 512 + tid;       // 0..4095
    const int wrw = id >> 6;            // 0..63 local n-row
    const int kb = (id & 63) * 16;      // byte in [0,1024)
    const int n = (wrw >> 4) * H_SZ + jt * 16 + (wrw & 15);
    const uint4 v = *(const uint4*)((const char*)WT + (size_t)n * 4096 + 2048 + kb);
    *(uint4*)((char*)WhL + wrw * 1024 + (kb ^ ((wrw & 7) << 4))) = v;
  }

  // ---- permanent B regs: Wh k in [1536,2048) ----
  const char* wrow = (const char*)WT + (size_t)(g * H_SZ + jt * 16 + lr) * 4096;
  bf16x8 breg[16];
#pragma unroll
  for (int q = 0; q < 16; ++q)
    breg[q] = *(const bf16x8*)(wrow + 3072 + q * 64 + ko * 16);

  // ---- per-thread output element state ----
  const int row = tid >> 4;     // 0..31
  const int col = tid & 15;
  const int b = b0 + row;
  const int j = jt * 16 + col;
  const size_t so = (size_t)b * H_SZ + j;
  float creg = c0[so] * (1.0f - reset[b]);

  const int swzl = (lr & 7) << 4;
  const char* aBase = (const char*)Ah + (mh * 16 + lr) * 2048;
  const char* bBase = (const char*)WhL + (g * 16 + lr) * 1024;

  for (int t = 0; t < T_STEPS; ++t) {
    // ---- A-stage: 32 h-rows via L3-coherent 8B loads -> LDS (swizzled) ----
    const ull_t* hsrc = (t == 0)
        ? (const ull_t*)hbf0
        : (const ull_t*)(hbuf + (size_t)(t & 1) * (B_SZ * H_SZ));
    ull_t av[16];
#pragma unroll
    for (int p = 0; p < 16; ++p) {
      const int id = p * 512 + tid;     // 0..8191
      const int ar = id >> 8;           // 0..31
      const int ac = id & 255;          // 8B chunk in row
      av[p] = __hip_atomic_load(hsrc + (size_t)(b0 + ar) * 256 + ac,
                                __ATOMIC_RELAXED, __HIP_MEMORY_SCOPE_AGENT);
    }
#pragma unroll
    for (int p = 0; p < 16; ++p) {
      const int id = p * 512 + tid;
      const int ar = id >> 8;
      const int ac = id & 255;
      *(ull_t*)((char*)Ah + ar * 2048 + ((ac * 8) ^ ((ar & 7) << 4))) = av[p];
    }
    const ull_t xwv =
        *(const ull_t*)(xwg + ((((size_t)t * 4 + btp) * 64 + jt) * 512 + tid) * 4);
    const float mn =
        (t < T_STEPS - 1) ? (1.0f - reset[(size_t)(t + 1) * B_SZ + b]) : 1.0f;
    __syncthreads();

    // ---- GEMM: 16x16 out per wave, K=1024 (LDS half + reg half) ----
    f32x4 acc = {};
#pragma unroll
    for (int ks = 0; ks < 16; ++ks) {
      bf16x8 a = *(const bf16x8*)(aBase + ((ks * 64 + ko * 16) ^ swzl));
      bf16x8 bb = *(const bf16x8*)(bBase + ((ks * 64 + ko * 16) ^ swzl));
      acc = __builtin_amdgcn_mfma_f32_16x16x32_bf16(a, bb, acc, 0, 0, 0);
    }
#pragma unroll
    for (int ks = 0; ks < 16; ++ks) {
      bf16x8 a = *(const bf16x8*)(aBase + (((16 + ks) * 64 + ko * 16) ^ swzl));
      acc = __builtin_amdgcn_mfma_f32_16x16x32_bf16(a, breg[ks], acc, 0, 0, 0);
    }
#pragma unroll
    for (int r = 0; r < 4; ++r) sc[mh][g][ko * 4 + r][lr] = acc[r];
    __syncthreads();

    // ---- fused elementwise: 512 threads -> 32 rows x 16 cols ----
    const float gi = sc[row >> 4][0][row & 15][col] + bf2f((ushort_t)xwv);
    const float gg = sc[row >> 4][1][row & 15][col] + bf2f((ushort_t)(xwv >> 16));
    const float gf = sc[row >> 4][2][row & 15][col] + bf2f((ushort_t)(xwv >> 32));
    const float go = sc[row >> 4][3][row & 15][col] + bf2f((ushort_t)(xwv >> 48));
    const float f = sigf(gf + 1.0f);
    const float cn = f * creg + sigf(gi) * tanhfast(gg);
    const float hn = sigf(go) * tanhfast(cn);
    out[(size_t)t * (B_SZ * H_SZ) + so] = hn;
    creg = cn * mn;

    if (t < T_STEPS - 1) {
      // premasked h_{t+1} via L3 write-through store
      __hip_atomic_store(hbuf + (size_t)((t + 1) & 1) * (B_SZ * H_SZ) + so,
                         f2bf(hn * mn), __ATOMIC_RELAXED, __HIP_MEMORY_SCOPE_AGENT);
      asm volatile("s_waitcnt vmcnt(0)" ::: "memory");  // drain to L3 (per wave)
      __syncthreads();
      if (tid == 0) {
        const uint_t t1 = 16u * (uint_t)(t + 1);
        if (atomicAdd(&bar[grp * 32], 1u) == t1 - 1u) {       // group closer
          if (atomicAdd(&bar[512], 1u) == t1 - 1u)            // global closer
            __hip_atomic_store(&bar[576], (uint_t)(t + 1),
                               __ATOMIC_RELAXED, __HIP_MEMORY_SCOPE_AGENT);
        }
        uint_t it = 0;
        while (__hip_atomic_load(&bar[576], __ATOMIC_RELAXED,
                                 __HIP_MEMORY_SCOPE_AGENT) < (uint_t)(t + 1)) {
          __builtin_amdgcn_s_sleep(2);
          if (++it > 100000u) break;  // bounded: fail visibly, don't hang
        }
      }
      __syncthreads();
    } else {
      float* hT = out + (size_t)T_STEPS * (B_SZ * H_SZ);
      float* cT = hT + (B_SZ * H_SZ);
      hT[so] = hn;
      cT[so] = cn;  // unmasked at last step
    }
  }
}

extern "C" void kernel_launch(void* const* d_in, const int* in_sizes, int n_in,
                              void* d_out, int out_size, void* d_ws, size_t ws_size,
                              hipStream_t stream) {
  (void)in_sizes; (void)n_in; (void)out_size; (void)ws_size;
  const float* x = (const float*)d_in[0];
  const float* h0 = (const float*)d_in[1];
  const float* c0 = (const float*)d_in[2];
  const float* reset = (const float*)d_in[3];
  const float* W = (const float*)d_in[4];
  const float* bias = (const float*)d_in[5];
  float* out = (float*)d_out;

  const size_t TB = (size_t)T_STEPS * B_SZ;  // 16384
  const size_t SE = (size_t)B_SZ * H_SZ;     // 131072

  // ws layout (4KB-aligned chunks)
  char* p = (char*)d_ws;
  uint_t* bar = (uint_t*)p;               p += 4096;
  ushort_t* WT = (ushort_t*)p;            p += (size_t)G4 * KW * 2;
  ushort_t* xbf = (ushort_t*)p;           p += TB * D_SZ * 2;
  ushort_t* xwg = (ushort_t*)p;           p += TB * G4 * 2;
  ushort_t* hbf0 = (ushort_t*)p;          p += SE * 2;
  ushort_t* hbuf = (ushort_t*)p;          p += 2 * SE * 2;

  hipMemsetAsync(bar, 0, 4096, stream);
  convert_x<<<dim3((int)(TB * D_SZ / 8 / 256)), 256, 0, stream>>>(x, xbf);
  transpose_w<<<dim3(KW / 32, G4 / 32), 256, 0, stream>>>(W, WT);
  init_state<<<dim3((int)((SE + 255) / 256)), 256, 0, stream>>>(h0, reset, hbf0);
  xw_mfma2<<<dim3(4096), 256, 0, stream>>>(xbf, WT, bias, xwg);

  lstm_persist2<<<dim3(256), 512, 0, stream>>>(hbf0, c0, reset, xwg, WT, out, hbuf, bar);
}